// Round 1
// baseline (59.464 us; speedup 1.0000x reference)
//
#include <hip/hip_runtime.h>

// MultiLIF forward: B=32, L=1024, K=512. 16384 chains (b,k), serial over t.
// Outputs concat: [spikes | series | v_seq], each B*L*K f32.
//
// Numerics (validated r1-r6): pass = zero spike flips + small v drift.
// Fused updates: v<-fma(v,.95,I), a<-fma(a,.99,s), th<-fma(1.5,a,1.5);
// s == s_hard exactly; reset = (fire ? -0.5 : v); snum exact int accum.
//
// r7 structure: redundant compute across TWELVE waves per 64-chain group
// (r6 used 6). Wave w handles stream (w>>2) and stores only slabs with
// slab%4 == (w&3). Aggregate store traffic unchanged (3 stores per
// element across the block); loads replicate 12x but dedup in L1/L2
// (FETCH stayed flat when replication went 1x->3x->6x). In-flight load
// bytes/CU double 24KB->48KB, waves/SIMD 1.5->3: attacks the MLP limit
// (r6 measured 5.65 TB/s effective vs 7.1 TB/s fill ceiling).
//
// Phase is a RUNTIME wave-uniform branch (not a template) to keep hot
// code ~10 KB (3 stream variants); 12 full template variants would be
// ~50 KB and thrash the 32 KB I$.

namespace {
constexpr int kL = 1024;
constexpr int kK = 512;
constexpr size_t kN = (size_t)32 * kL * kK;      // per-output elements
constexpr float kVD = 1.0f - 1.0f / 20.0f;       // 0.95f
constexpr float kAD = 1.0f - 1.0f / 100.0f;      // 0.99f
}

// One 16-step slab, compute only (no stores). PFETCH: prefetch t+16.
template <bool PFETCH>
__device__ __forceinline__ void slab_nostore(const float* __restrict__ ip,
                                             unsigned& ioff, float (&ibuf)[16],
                                             float& v, float& a, float& snum,
                                             float& th) {
#pragma unroll
    for (int j = 0; j < 16; ++j) {
        const float It = ibuf[j];
        if (PFETCH) { ibuf[j] = ip[ioff]; ioff += kK; }   // prefetch t+16
        v = __fmaf_rn(v, kVD, It);                        // leak + input
        const bool fire = (v >= th);
        const float s = fire ? 1.0f : 0.0f;
        snum += s;                                        // exact int accum
        v = fire ? -0.5f : v;                             // exact reset
        a = __fmaf_rn(a, kAD, s);
        th = __fmaf_rn(1.5f, a, 1.5f);
    }
}

// One 16-step slab that stores stream W. W: 0=spikes,1=series,2=v_seq.
template <int W, bool PFETCH>
__device__ __forceinline__ void slab_store(const float* __restrict__ ip,
                                           unsigned& ioff,
                                           float* __restrict__ outp,
                                           unsigned& off, float (&ibuf)[16],
                                           float& v, float& a, float& snum,
                                           float& th) {
#pragma unroll
    for (int j = 0; j < 16; ++j) {
        const float It = ibuf[j];
        if (PFETCH) { ibuf[j] = ip[ioff]; ioff += kK; }   // prefetch t+16
        v = __fmaf_rn(v, kVD, It);                        // leak + input
        const bool fire = (v >= th);
        const float s = fire ? 1.0f : 0.0f;
        snum += s;                                        // exact int accum
        const float val = (W == 0) ? s : (W == 1) ? snum : v;
        __builtin_nontemporal_store(val, outp + off);
        v = fire ? -0.5f : v;                             // exact reset
        a = __fmaf_rn(a, kAD, s);
        th = __fmaf_rn(1.5f, a, 1.5f);
        off += kK;
    }
}

// Full 1024-step chain; stores only slabs with slab%4 == ph (16 slabs).
template <int W>
__device__ __forceinline__ void run_chain(const float* __restrict__ ip,
                                          float* __restrict__ outp,
                                          const int ph) {
    float v = 0.0f, a = 0.0f, snum = 0.0f, th = 1.5f;

    float ibuf[16];
#pragma unroll
    for (int j = 0; j < 16; ++j) ibuf[j] = ip[(size_t)j * kK];
    unsigned ioff = 16u * kK;   // next prefetch element offset (t=16)
    unsigned off = 0;           // current store element offset (t*kK)

    // slabs 0..62 all prefetch (slab 62 prefetches t=1008..1023).
#pragma unroll 1
    for (int slab = 0; slab < 63; ++slab) {
        if ((slab & 3) == ph) {
            slab_store<W, true>(ip, ioff, outp, off, ibuf, v, a, snum, th);
        } else {
            slab_nostore<true>(ip, ioff, ibuf, v, a, snum, th);
            off += 16u * kK;
        }
    }
    // slab 63 (phase 3), no prefetch.
    if (ph == 3) {
        slab_store<W, false>(ip, ioff, outp, off, ibuf, v, a, snum, th);
    } else {
        slab_nostore<false>(ip, ioff, ibuf, v, a, snum, th);
    }
}

__global__ __launch_bounds__(768) void multilif_fwd(const float* __restrict__ I,
                                                    float* __restrict__ out) {
    const int lane = (int)threadIdx.x & 63;
    const int w = (int)threadIdx.x >> 6;             // 0..11
    const int W = w >> 2;                            // stream 0..2
    const int ph = w & 3;                            // slab phase 0..3
    const int wb0 = (int)blockIdx.x * 64;            // first chain of group
    const size_t base = (size_t)(wb0 >> 9) * ((size_t)kL * kK)
                      + (size_t)(wb0 & (kK - 1)) + (size_t)lane;
    const float* __restrict__ ip = I + base;
    float* __restrict__ outp = out + (size_t)W * kN + base;

    if (W == 0)      run_chain<0>(ip, outp, ph);     // spikes
    else if (W == 1) run_chain<1>(ip, outp, ph);     // series
    else             run_chain<2>(ip, outp, ph);     // v_seq
}

extern "C" void kernel_launch(void* const* d_in, const int* in_sizes, int n_in,
                              void* d_out, int out_size, void* d_ws, size_t ws_size,
                              hipStream_t stream) {
    const float* I = (const float*)d_in[0];
    float* out = (float*)d_out;
    // 256 chain-groups x 12 redundant-compute waves = 256 blocks x 768 thr.
    dim3 grid((32 * kK) / 64), block(768);
    hipLaunchKernelGGL(multilif_fwd, grid, block, 0, stream, I, out);
}

// Round 2
// 50.854 us; speedup vs baseline: 1.1693x; 1.1693x over previous
//
#include <hip/hip_runtime.h>

// MultiLIF forward: B=32, L=1024, K=512. 16384 chains (b,k), serial over t.
// Outputs concat: [spikes | series | v_seq], each B*L*K f32.
//
// Numerics (validated r1-r6): pass = zero spike flips + small v drift.
// Fused updates: v<-fma(v,.95,I), a<-fma(a,.99,s), th<-fma(1.5,a,1.5);
// s == s_hard exactly; reset = (fire ? -0.5 : v); snum exact int accum.
//
// r8 structure: identical to r6 (best known, 47.4 us) EXCEPT the prefetch
// distance is 32 steps instead of 16, via a two-half ring (ibufA/ibufB).
// 6 redundant-compute waves per 64-chain group; wave w stores stream
// (w>>1) on alternate 16-step slabs (parity w&1).
//
// Why: at the 6.3 TB/s mixed ceiling per-CU step time is ~41.6 ns; a
// 16-deep ring covers only ~666 ns of load latency vs ~900 ns HBM miss,
// so the leader wave was latency-stalled (r6 measured 46.3 ns/step).
// 32-deep = ~1.33 us cover. Codegen is unchanged otherwise: slabs stay
// 16-step template-specialized straightline code (r7 showed that a
// runtime store/no-store branch forces conservative vmcnt waits at the
// control-flow join -> 25% regression; vmcnt retires in issue order, so
// exact static counts per path are essential).

namespace {
constexpr int kL = 1024;
constexpr int kK = 512;
constexpr size_t kN = (size_t)32 * kL * kK;      // per-output elements
constexpr float kVD = 1.0f - 1.0f / 20.0f;       // 0.95f
constexpr float kAD = 1.0f - 1.0f / 100.0f;      // 0.99f
}

// One 16-step slab. W: stream (0=spikes,1=series,2=v). STORE: this wave
// stores this slab. PFETCH: prefetch t+32 into this half of the ring.
template <int W, bool STORE, bool PFETCH>
__device__ __forceinline__ void slab16(const float* __restrict__ ip,
                                       unsigned& ioff,
                                       float* __restrict__ outp, unsigned& off,
                                       float (&ibuf)[16], float& v, float& a,
                                       float& snum, float& th) {
#pragma unroll
    for (int j = 0; j < 16; ++j) {
        const float It = ibuf[j];
        if (PFETCH) { ibuf[j] = ip[ioff]; ioff += kK; }   // prefetch t+32
        v = __fmaf_rn(v, kVD, It);                        // leak + input
        const bool fire = (v >= th);
        const float s = fire ? 1.0f : 0.0f;
        snum += s;                                        // exact int accum
        if (STORE) {
            const float val = (W == 0) ? s : (W == 1) ? snum : v;
            __builtin_nontemporal_store(val, outp + off);
        }
        v = fire ? -0.5f : v;                             // exact reset
        a = __fmaf_rn(a, kAD, s);
        th = __fmaf_rn(1.5f, a, 1.5f);
        off += kK;
    }
}

// Full 1024-step chain; stores only slabs with parity PAR (64 slabs).
// Two-half ring: even slabs consume/refill ibufA, odd slabs ibufB, each
// refilling with data 32 steps ahead of what it just consumed.
template <int W, int PAR>
__device__ __forceinline__ void run_chain(const float* __restrict__ ip,
                                          float* __restrict__ outp) {
    float v = 0.0f, a = 0.0f, snum = 0.0f, th = 1.5f;

    float ibufA[16], ibufB[16];
#pragma unroll
    for (int j = 0; j < 16; ++j) ibufA[j] = ip[(size_t)j * kK];        // t 0..15
#pragma unroll
    for (int j = 0; j < 16; ++j) ibufB[j] = ip[(size_t)(16 + j) * kK]; // t 16..31
    unsigned ioff = 32u * kK;   // next prefetch element offset (t=32)
    unsigned off = 0;           // current store element offset (t*kK)

    // slabs 0..61 in pairs (even->A, odd->B), all prefetching t+32
#pragma unroll 1
    for (int c = 0; c < 31; ++c) {
        slab16<W, PAR == 0, true>(ip, ioff, outp, off, ibufA, v, a, snum, th);
        slab16<W, PAR == 1, true>(ip, ioff, outp, off, ibufB, v, a, snum, th);
    }
    // slabs 62 (A) and 63 (B): consume t=992..1023, no prefetch
    slab16<W, PAR == 0, false>(ip, ioff, outp, off, ibufA, v, a, snum, th);
    slab16<W, PAR == 1, false>(ip, ioff, outp, off, ibufB, v, a, snum, th);
}

__global__ __launch_bounds__(384) void multilif_fwd(const float* __restrict__ I,
                                                    float* __restrict__ out) {
    const int lane = (int)threadIdx.x & 63;
    const int w = (int)threadIdx.x >> 6;             // 0..5
    const int wb0 = (int)blockIdx.x * 64;            // first chain of group
    const size_t base = (size_t)(wb0 >> 9) * ((size_t)kL * kK)
                      + (size_t)(wb0 & (kK - 1)) + (size_t)lane;
    const float* __restrict__ ip = I + base;
    float* __restrict__ outp = out + (size_t)(w >> 1) * kN + base;

    switch (w) {
        case 0: run_chain<0, 0>(ip, outp); break;   // spikes, even slabs
        case 1: run_chain<0, 1>(ip, outp); break;   // spikes, odd slabs
        case 2: run_chain<1, 0>(ip, outp); break;   // series, even slabs
        case 3: run_chain<1, 1>(ip, outp); break;   // series, odd slabs
        case 4: run_chain<2, 0>(ip, outp); break;   // v_seq, even slabs
        default: run_chain<2, 1>(ip, outp); break;  // v_seq, odd slabs
    }
}

extern "C" void kernel_launch(void* const* d_in, const int* in_sizes, int n_in,
                              void* d_out, int out_size, void* d_ws, size_t ws_size,
                              hipStream_t stream) {
    const float* I = (const float*)d_in[0];
    float* out = (float*)d_out;
    // 256 chain-groups x 6 redundant-compute waves = 256 blocks x 384 thr.
    dim3 grid((32 * kK) / 64), block(384);
    hipLaunchKernelGGL(multilif_fwd, grid, block, 0, stream, I, out);
}